// Round 5
// baseline (183.338 us; speedup 1.0000x reference)
//
#include <hip/hip_runtime.h>

typedef __attribute__((ext_vector_type(8))) short short8;
typedef __attribute__((ext_vector_type(16))) float floatx16;
typedef unsigned short u16;
typedef unsigned int u32;

#define NB 8
#define CI 512
#define CO 512
#define HH 64
#define WW 64
#define HP 66
#define WP 66
#define BK 64

__device__ __forceinline__ u16 f2bf(float f) {
  u32 u = __builtin_bit_cast(u32, f);
  u += 0x7fffu + ((u >> 16) & 1u);
  return (u16)(u >> 16);
}

__device__ __forceinline__ void gload16(const void* g, void* l) {
  __builtin_amdgcn_global_load_lds(
      (const __attribute__((address_space(1))) unsigned int*)g,
      (__attribute__((address_space(3))) unsigned int*)l, 16, 0, 0);
}

// s[b,i] = coef * dot(y[b,:], affine_w[i,:]) + affine_b[i] + 1
__global__ __launch_bounds__(256) void k_style(
    const float* __restrict__ y, const float* __restrict__ aw,
    const float* __restrict__ ab, float* __restrict__ s)
{
  const int wid = blockIdx.x * 4 + (threadIdx.x >> 6);
  const int lane = threadIdx.x & 63;
  const int b = wid >> 9, i = wid & 511;
  float sum = 0.f;
  #pragma unroll
  for (int j = 0; j < 8; ++j) {
    const int k = lane + (j << 6);
    sum += y[b * CI + k] * aw[i * CI + k];
  }
  #pragma unroll
  for (int off = 32; off; off >>= 1) sum += __shfl_xor(sum, off);
  if (lane == 0) s[wid] = sum * 0.044194173824159216f + ab[i] + 1.0f;
}

// fused: wsum[o,i] = sum_t weight[o,i,t]^2 ; wb[(o*9+t)*512+i] = bf16(weight[o,i,t])
__global__ __launch_bounds__(256) void k_wprep(
    const float* __restrict__ wt, float* __restrict__ wsum, u16* __restrict__ wbv)
{
  const int idx = blockIdx.x * 256 + threadIdx.x;   // o*512+i
  const int i = idx & 511;
  const int o = idx >> 9;
  const float* p = wt + (size_t)idx * 9;
  float v[9];
  float sum = 0.f;
  #pragma unroll
  for (int t = 0; t < 9; ++t) { v[t] = p[t]; sum += v[t] * v[t]; }
  wsum[idx] = sum;
  #pragma unroll
  for (int t = 0; t < 9; ++t) wbv[(((o * 9 + t) << 9) | i)] = f2bf(v[t]);
}

// d[b,o] = rsqrt(sum_i wsum[o,i]*s[b,i]^2 + 1e-4)
__global__ __launch_bounds__(256) void k_demod(
    const float* __restrict__ wsum, const float* __restrict__ s,
    float* __restrict__ d)
{
  const int wid = blockIdx.x * 4 + (threadIdx.x >> 6);
  const int lane = threadIdx.x & 63;
  const int b = wid >> 9, o = wid & 511;
  float sum = 0.f;
  #pragma unroll
  for (int j = 0; j < 8; ++j) {
    const int i = lane + (j << 6);
    const float sv = s[b * CI + i];
    sum += wsum[o * CI + i] * sv * sv;
  }
  #pragma unroll
  for (int off = 32; off; off >>= 1) sum += __shfl_xor(sum, off);
  if (lane == 0) d[wid] = rsqrtf(sum + 1e-4f);
}

// xs[b, h+1, w+1, i] (NHWC, 66x66 padded, bf16) = x[b,i,h,w] * s[b,i]
// also zeroes its own slice of the halo border (replaces the 35 MB memset).
__global__ __launch_bounds__(256) void k_xform(
    const float* __restrict__ x, const float* __restrict__ s,
    u16* __restrict__ xs)
{
  __shared__ __align__(16) u16 lds[64 * 72];
  const int blk = blockIdx.x;          // ((b*64+h)*8 + ic)
  const int ic = blk & 7;
  const int h = (blk >> 3) & 63;
  const int b = blk >> 9;
  const int i0 = ic << 6;
  const int t = threadIdx.x;
  const int w = t & 63;
  const int i4 = t >> 6;
  #pragma unroll
  for (int p = 0; p < 16; ++p) {
    const int ii = i4 + (p << 2);
    const float xv = x[((size_t)(b * CI + i0 + ii) * HH + h) * WW + w];
    const float sv = s[b * CI + i0 + ii];
    lds[w * 72 + ii] = f2bf(xv * sv);
  }
  // halo: side columns w=0,65 of this row
  const uint4 z4 = {0u, 0u, 0u, 0u};
  if (t < 16) {
    const int wside = (t < 8) ? 0 : 65;
    const int q = t & 7;
    *(uint4*)&xs[((size_t)(b * HP + h + 1) * WP + wside) * CI + i0 + (q << 3)] = z4;
  }
  // halo: full rows 0 and 65 (h==0 blocks only)
  if (h == 0) {
    for (int idx = t; idx < 2 * 66 * 8; idx += 256) {
      const int row = (idx < 528) ? 0 : 65;
      const int rem = (idx < 528) ? idx : idx - 528;
      const int wz = rem >> 3;
      const int q = rem & 7;
      *(uint4*)&xs[((size_t)(b * HP + row) * WP + wz) * CI + i0 + (q << 3)] = z4;
    }
  }
  __syncthreads();
  const int w2 = t >> 2;
  const int q = t & 3;
  const uint4* src = (const uint4*)&lds[w2 * 72 + (q << 4)];
  const uint4 v0 = src[0];
  const uint4 v1 = src[1];
  u16* dst = xs + ((size_t)(b * HP + h + 1) * WP + (w2 + 1)) * CI + i0 + (q << 4);
  *(uint4*)dst = v0;
  *((uint4*)dst + 1) = v1;
}

// ---------------------------------------------------------------------------
// implicit-GEMM conv, 256x256 deep-pipelined, MFMA 32x32x16 bf16 (2495 TF
// shape ceiling vs 2075 for 16x16x32; identical LDS traffic & schedule).
// BM=256 (O), BN=256 (pixels = 4 rows x 64 w), BK=64, K = 9 taps x 512 = 72 tiles.
// 512 threads, 8 waves (2M x 4N), per-wave C = 128x64 = 4x2 tiles of 32x32.
// LDS 128 KB: double-buffered A[256][64] + B[256][64] bf16, XOR slot swizzle.
// Stage split fine-grained: B(t+2) at P3 (lB fully read after P2),
// A(t+2) at P4 (lA fully read after P3). vmcnt(8) once per tile.
// ---------------------------------------------------------------------------
__global__ __launch_bounds__(512, 2) void k_conv(
    const u16* __restrict__ xs, const u16* __restrict__ wb,
    const float* __restrict__ dmod, const float* __restrict__ bias,
    float* __restrict__ out)
{
  __shared__ __align__(16) u16 lA[2 * 16384];
  __shared__ __align__(16) u16 lB[2 * 16384];

  const int blk = blockIdx.x;
  const int nt = blk & 15;
  const int mt = (blk >> 4) & 1;
  const int b  = blk >> 5;
  const int ob = mt << 8;
  const int p0 = nt << 8;

  const int tid = threadIdx.x;
  const int wid = tid >> 6;
  const int lane = tid & 63;
  const int r5 = lane & 31;          // MFMA row/col within 32
  const int hi = lane >> 5;          // K-half selector
  const int wr  = wid >> 2;          // wave M index (0..1)
  const int wc  = wid & 3;           // wave N index (0..3)

  // staging lane geometry: gload16 stages 8 rows x 8 slots (1 KB), LDS linear.
  // source column pre-swizzled: lane l fetches slot (l&7)^(l>>3) of its row.
  const int lr = lane >> 3;
  const int ls = lane & 7;
  const int swz = ls ^ lr;

  u32 aoffs[4], boffs[4], ldst[4];
  #pragma unroll
  for (int g = 0; g < 4; ++g) {
    const int rg = (wid << 5) + (g << 3);        // row-group base 0..255
    aoffs[g] = (u32)((ob + rg + lr) * 4608 + (swz << 3));
    const int p = p0 + rg + lr;
    boffs[g] = (u32)(((b * HP + (p >> 6)) * WP + (p & 63)) * 512 + (swz << 3));
    ldst[g] = (u32)(rg << 6);
  }

  // ds_read: element offset within a row for k-step ks: slot (ks*2+hi) ^ (row&7),
  // row&7 == lane&7 (all tile row offsets are multiples of 8/32).
  u32 sS[4];
  #pragma unroll
  for (int ks = 0; ks < 4; ++ks)
    sS[ks] = (u32)((((ks * 2 + hi) ^ (lane & 7)) << 3));
  const u32 aRead = (u32)((((wr << 7) + r5) << 6));
  const u32 bRead = (u32)((((wc << 6) + r5) << 6));

  floatx16 acc[4][2];
  #pragma unroll
  for (int m = 0; m < 4; ++m)
    #pragma unroll
    for (int n = 0; n < 2; ++n)
      #pragma unroll
      for (int r = 0; r < 16; ++r)
        acc[m][n][r] = 0.f;

  short8 a0[2][4], b0[4], b1[4];

#define STAGE_B(KC, C) do {                                                   \
    const int kc2_ = (KC);                                                    \
    const int tap_ = kc2_ >> 3;                                               \
    const int kh_ = tap_ / 3;                                                 \
    const int kw_ = tap_ - kh_ * 3;                                           \
    const u32 bt_ = (u32)(((kh_ * WP + kw_) << 9) + ((kc2_ & 7) << 6));       \
    _Pragma("unroll")                                                         \
    for (int g = 0; g < 4; ++g)                                               \
      gload16(xs + boffs[g] + bt_, &lB[((C) << 14) + ldst[g]]);               \
  } while (0)

#define STAGE_A(KC, C) do {                                                   \
    const u32 at_ = (u32)((KC) << 6);                                         \
    _Pragma("unroll")                                                         \
    for (int g = 0; g < 4; ++g)                                               \
      gload16(wb + aoffs[g] + at_, &lA[((C) << 14) + ldst[g]]);               \
  } while (0)

#define READ_A(PA, MH) do {                                                   \
    _Pragma("unroll")                                                         \
    for (int mi = 0; mi < 2; ++mi)                                            \
      _Pragma("unroll")                                                       \
      for (int ks = 0; ks < 4; ++ks)                                          \
        a0[mi][ks] = *(const short8*)((PA) + (((MH)*2+mi) << 11) + sS[ks]);   \
  } while (0)

#define READ_B(PB, NH, BV) do {                                               \
    _Pragma("unroll")                                                         \
    for (int ks = 0; ks < 4; ++ks)                                            \
      BV[ks] = *(const short8*)((PB) + ((NH) << 11) + sS[ks]);                \
  } while (0)

#define MFMA_Q(MH, NH, BV) do {                                               \
    _Pragma("unroll")                                                         \
    for (int ks = 0; ks < 4; ++ks)                                            \
      _Pragma("unroll")                                                       \
      for (int mi = 0; mi < 2; ++mi)                                          \
        acc[(MH)*2+mi][NH] = __builtin_amdgcn_mfma_f32_32x32x16_bf16(         \
            a0[mi][ks], BV[ks], acc[(MH)*2+mi][NH], 0, 0, 0);                 \
  } while (0)

#define BODY(T, DOSTAGE, WMODE) do {                                          \
    const int c_ = (T) & 1;                                                   \
    const u16* pA = lA + (c_ << 14) + aRead;                                  \
    const u16* pB = lB + (c_ << 14) + bRead;                                  \
    /* P1 */                                                                  \
    READ_A(pA, 0);                                                            \
    READ_B(pB, 0, b0);                                                        \
    __builtin_amdgcn_s_barrier();                                             \
    __builtin_amdgcn_s_setprio(1); MFMA_Q(0, 0, b0); __builtin_amdgcn_s_setprio(0); \
    __builtin_amdgcn_s_barrier();                                             \
    /* P2 */                                                                  \
    READ_B(pB, 1, b1);                                                        \
    __builtin_amdgcn_s_barrier();                                             \
    __builtin_amdgcn_s_setprio(1); MFMA_Q(0, 1, b1); __builtin_amdgcn_s_setprio(0); \
    __builtin_amdgcn_s_barrier();                                             \
    /* P3: stage B(t+2) interleaved with A1 reads (lB fully read by P2) */    \
    __builtin_amdgcn_sched_barrier(0);                                        \
    if (DOSTAGE) STAGE_B((T) + 2, c_);                                        \
    READ_A(pA, 1);                                                            \
    __builtin_amdgcn_s_barrier();                                             \
    __builtin_amdgcn_s_setprio(1); MFMA_Q(1, 1, b1); __builtin_amdgcn_s_setprio(0); \
    __builtin_amdgcn_s_barrier();                                             \
    /* P4: stage A(t+2), then last quadrant */                                \
    __builtin_amdgcn_sched_barrier(0);                                        \
    if (DOSTAGE) STAGE_A((T) + 2, c_);                                        \
    __builtin_amdgcn_s_setprio(1); MFMA_Q(1, 0, b0); __builtin_amdgcn_s_setprio(0); \
    if (WMODE == 1)      asm volatile("s_waitcnt vmcnt(8)" ::: "memory");     \
    else if (WMODE == 2) asm volatile("s_waitcnt vmcnt(0)" ::: "memory");     \
    __builtin_amdgcn_sched_barrier(0);                                        \
    if (WMODE != 0) __builtin_amdgcn_s_barrier();                             \
  } while (0)

  // prologue: stage tiles 0 and 1, wait for tile 0 (8 newer stay in flight)
  STAGE_B(0, 0); STAGE_A(0, 0);
  STAGE_B(1, 1); STAGE_A(1, 1);
  asm volatile("s_waitcnt vmcnt(8)" ::: "memory");
  __builtin_amdgcn_sched_barrier(0);
  __builtin_amdgcn_s_barrier();

  for (int t = 0; t < 70; ++t) BODY(t, 1, 1);
  BODY(70, 0, 2);
  BODY(71, 0, 0);

#undef STAGE_B
#undef STAGE_A
#undef READ_A
#undef READ_B
#undef MFMA_Q
#undef BODY

  // epilogue: out = acc * d[b,o] + bias[o]
  // 32x32 C/D: col = lane&31, row = (reg&3) + 8*(reg>>2) + 4*(lane>>5)
  #pragma unroll
  for (int m = 0; m < 4; ++m) {
    #pragma unroll
    for (int reg = 0; reg < 16; ++reg) {
      const int row = (reg & 3) + ((reg >> 2) << 3) + (hi << 2);
      const int o = ob + (wr << 7) + (m << 5) + row;
      const float dm = dmod[b * CO + o];
      const float bs = bias[o];
      float* po = out + (((size_t)(b * CO + o)) << 12) + p0 + (wc << 6) + r5;
      po[0]  = acc[m][0][reg] * dm + bs;
      po[32] = acc[m][1][reg] * dm + bs;
    }
  }
}

extern "C" void kernel_launch(void* const* d_in, const int* in_sizes, int n_in,
                              void* d_out, int out_size, void* d_ws, size_t ws_size,
                              hipStream_t stream) {
  const float* x    = (const float*)d_in[0];
  const float* y    = (const float*)d_in[1];
  const float* aw   = (const float*)d_in[2];
  const float* ab   = (const float*)d_in[3];
  const float* wt   = (const float*)d_in[4];
  const float* bias = (const float*)d_in[5];
  float* out = (float*)d_out;

  char* ws = (char*)d_ws;
  const size_t XS_BYTES = (size_t)NB * HP * WP * CI * 2;     // 35,684,352
  const size_t WB_BYTES = (size_t)CO * 9 * CI * 2;           //  4,718,592
  const size_t WS_BYTES = (size_t)CO * CI * 4;               //  1,048,576
  u16* xsb    = (u16*)ws;
  u16* wbuf   = (u16*)(ws + XS_BYTES);
  float* wsum = (float*)(ws + XS_BYTES + WB_BYTES);
  float* sbuf = (float*)(ws + XS_BYTES + WB_BYTES + WS_BYTES);
  float* dbuf = sbuf + NB * CI;

  k_style<<<dim3(1024), dim3(256), 0, stream>>>(y, aw, ab, sbuf);
  k_wprep<<<dim3(1024), dim3(256), 0, stream>>>(wt, wsum, wbuf);
  k_demod<<<dim3(1024), dim3(256), 0, stream>>>(wsum, sbuf, dbuf);
  k_xform<<<dim3(4096), dim3(256), 0, stream>>>(x, sbuf, xsb);
  k_conv <<<dim3(256), dim3(512), 0, stream>>>(xsb, wbuf, dbuf, bias, out);
}

// Round 6
// 163.741 us; speedup vs baseline: 1.1197x; 1.1197x over previous
//
#include <hip/hip_runtime.h>

typedef __attribute__((ext_vector_type(8))) short short8;
typedef __attribute__((ext_vector_type(4))) float floatx4;
typedef unsigned short u16;
typedef unsigned int u32;

#define NB 8
#define CI 512
#define CO 512
#define HH 64
#define WW 64
#define HP 66
#define WP 66
#define BK 64

__device__ __forceinline__ u16 f2bf(float f) {
  u32 u = __builtin_bit_cast(u32, f);
  u += 0x7fffu + ((u >> 16) & 1u);
  return (u16)(u >> 16);
}

__device__ __forceinline__ void gload16(const void* g, void* l) {
  __builtin_amdgcn_global_load_lds(
      (const __attribute__((address_space(1))) unsigned int*)g,
      (__attribute__((address_space(3))) unsigned int*)l, 16, 0, 0);
}

// s[b,i] = coef * dot(y[b,:], affine_w[i,:]) + affine_b[i] + 1
__global__ __launch_bounds__(256) void k_style(
    const float* __restrict__ y, const float* __restrict__ aw,
    const float* __restrict__ ab, float* __restrict__ s)
{
  const int wid = blockIdx.x * 4 + (threadIdx.x >> 6);
  const int lane = threadIdx.x & 63;
  const int b = wid >> 9, i = wid & 511;
  float sum = 0.f;
  #pragma unroll
  for (int j = 0; j < 8; ++j) {
    const int k = lane + (j << 6);
    sum += y[b * CI + k] * aw[i * CI + k];
  }
  #pragma unroll
  for (int off = 32; off; off >>= 1) sum += __shfl_xor(sum, off);
  if (lane == 0) s[wid] = sum * 0.044194173824159216f + ab[i] + 1.0f;
}

// fused: wsum[o,i] = sum_t weight[o,i,t]^2 ; wb[(o*9+t)*512+i] = bf16(weight[o,i,t])
__global__ __launch_bounds__(256) void k_wprep(
    const float* __restrict__ wt, float* __restrict__ wsum, u16* __restrict__ wbv)
{
  const int idx = blockIdx.x * 256 + threadIdx.x;   // o*512+i
  const int i = idx & 511;
  const int o = idx >> 9;
  const float* p = wt + (size_t)idx * 9;
  float v[9];
  float sum = 0.f;
  #pragma unroll
  for (int t = 0; t < 9; ++t) { v[t] = p[t]; sum += v[t] * v[t]; }
  wsum[idx] = sum;
  #pragma unroll
  for (int t = 0; t < 9; ++t) wbv[(((o * 9 + t) << 9) | i)] = f2bf(v[t]);
}

// d[b,o] = rsqrt(sum_i wsum[o,i]*s[b,i]^2 + 1e-4)
__global__ __launch_bounds__(256) void k_demod(
    const float* __restrict__ wsum, const float* __restrict__ s,
    float* __restrict__ d)
{
  const int wid = blockIdx.x * 4 + (threadIdx.x >> 6);
  const int lane = threadIdx.x & 63;
  const int b = wid >> 9, o = wid & 511;
  float sum = 0.f;
  #pragma unroll
  for (int j = 0; j < 8; ++j) {
    const int i = lane + (j << 6);
    const float sv = s[b * CI + i];
    sum += wsum[o * CI + i] * sv * sv;
  }
  #pragma unroll
  for (int off = 32; off; off >>= 1) sum += __shfl_xor(sum, off);
  if (lane == 0) d[wid] = rsqrtf(sum + 1e-4f);
}

// xs[b, h+1, w+1, i] (NHWC, 66x66 padded, bf16) = x[b,i,h,w] * s[b,i]
// also zeroes its own slice of the halo border (replaces the 35 MB memset).
__global__ __launch_bounds__(256) void k_xform(
    const float* __restrict__ x, const float* __restrict__ s,
    u16* __restrict__ xs)
{
  __shared__ __align__(16) u16 lds[64 * 72];
  const int blk = blockIdx.x;          // ((b*64+h)*8 + ic)
  const int ic = blk & 7;
  const int h = (blk >> 3) & 63;
  const int b = blk >> 9;
  const int i0 = ic << 6;
  const int t = threadIdx.x;
  const int w = t & 63;
  const int i4 = t >> 6;
  #pragma unroll
  for (int p = 0; p < 16; ++p) {
    const int ii = i4 + (p << 2);
    const float xv = x[((size_t)(b * CI + i0 + ii) * HH + h) * WW + w];
    const float sv = s[b * CI + i0 + ii];
    lds[w * 72 + ii] = f2bf(xv * sv);
  }
  // halo: side columns w=0,65 of this row
  const uint4 z4 = {0u, 0u, 0u, 0u};
  if (t < 16) {
    const int wside = (t < 8) ? 0 : 65;
    const int q = t & 7;
    *(uint4*)&xs[((size_t)(b * HP + h + 1) * WP + wside) * CI + i0 + (q << 3)] = z4;
  }
  // halo: full rows 0 and 65 (h==0 blocks only)
  if (h == 0) {
    for (int idx = t; idx < 2 * 66 * 8; idx += 256) {
      const int row = (idx < 528) ? 0 : 65;
      const int rem = (idx < 528) ? idx : idx - 528;
      const int wz = rem >> 3;
      const int q = rem & 7;
      *(uint4*)&xs[((size_t)(b * HP + row) * WP + wz) * CI + i0 + (q << 3)] = z4;
    }
  }
  __syncthreads();
  const int w2 = t >> 2;
  const int q = t & 3;
  const uint4* src = (const uint4*)&lds[w2 * 72 + (q << 4)];
  const uint4 v0 = src[0];
  const uint4 v1 = src[1];
  u16* dst = xs + ((size_t)(b * HP + h + 1) * WP + (w2 + 1)) * CI + i0 + (q << 4);
  *(uint4*)dst = v0;
  *((uint4*)dst + 1) = v1;
}

// ---------------------------------------------------------------------------
// implicit-GEMM conv, 256x256 deep-pipelined, MFMA 16x16x32 bf16.
// BM=256 (O), BN=256 (pixels = 4 rows x 64 w), BK=64, K = 9 taps x 512 = 72 tiles.
// 512 threads, 8 waves (2M x 4N), per-wave C = 128x64 (8m x 4n frags).
// LDS 128 KB: double-buffered A[256][64] + B[256][64] bf16, XOR slot swizzle.
// 3 phases/tile (5 barriers, was 8): S1 reads A0+B0+B1 -> 32 MFMA;
// S2 stage B(t+2) + read A1 -> 16 MFMA; S3 stage A(t+2) + 16 MFMA.
// No post-stage sched_barrier pins (m141: order-pinning defeats scheduler);
// only pre-stage fences keep stage writes below the protecting barrier.
// vmcnt(8) once per tile (t+2's 8 loads stay in flight -> waits for t+1).
// ---------------------------------------------------------------------------
__global__ __launch_bounds__(512, 2) void k_conv(
    const u16* __restrict__ xs, const u16* __restrict__ wb,
    const float* __restrict__ dmod, const float* __restrict__ bias,
    float* __restrict__ out)
{
  __shared__ __align__(16) u16 lA[2 * 16384];
  __shared__ __align__(16) u16 lB[2 * 16384];

  const int blk = blockIdx.x;
  const int nt = blk & 15;
  const int mt = (blk >> 4) & 1;
  const int b  = blk >> 5;
  const int ob = mt << 8;
  const int p0 = nt << 8;

  const int tid = threadIdx.x;
  const int wid = tid >> 6;
  const int lane = tid & 63;
  const int col = lane & 15;
  const int k8  = lane >> 4;
  const int wr  = wid >> 2;          // wave M index (0..1)
  const int wc  = wid & 3;           // wave N index (0..3)

  // staging lane geometry: gload16 stages 8 rows x 8 slots (1 KB), LDS linear.
  // source column pre-swizzled: lane l fetches slot (l&7)^(l>>3) of its row.
  const int lr = lane >> 3;
  const int ls = lane & 7;
  const int swz = ls ^ lr;

  u32 aoffs[4], boffs[4], ldst[4];
  #pragma unroll
  for (int g = 0; g < 4; ++g) {
    const int rg = (wid << 5) + (g << 3);        // row-group base 0..255
    aoffs[g] = (u32)((ob + rg + lr) * 4608 + (swz << 3));
    const int p = p0 + rg + lr;
    boffs[g] = (u32)(((b * HP + (p >> 6)) * WP + (p & 63)) * 512 + (swz << 3));
    ldst[g] = (u32)(rg << 6);
  }

  // ds_read swizzled slot offsets (elements): slot (kk*4+k8) ^ (row&7), row&7 == col&7
  const u32 sA0 = (u32)(((0 + k8) ^ (col & 7)) << 3);
  const u32 sA1 = (u32)(((4 + k8) ^ (col & 7)) << 3);
  const u32 aRead = (u32)((((wr << 7) + col) << 6));
  const u32 bRead = (u32)((((wc << 6) + col) << 6));

  floatx4 acc[8][4];
  #pragma unroll
  for (int m = 0; m < 8; ++m)
    #pragma unroll
    for (int n = 0; n < 4; ++n)
      acc[m][n] = (floatx4){0.f, 0.f, 0.f, 0.f};

  short8 a0[4][2], b0[2][2], b1[2][2];

#define STAGE_B(KC, C) do {                                                   \
    const int kc2_ = (KC);                                                    \
    const int tap_ = kc2_ >> 3;                                               \
    const int kh_ = tap_ / 3;                                                 \
    const int kw_ = tap_ - kh_ * 3;                                           \
    const u32 bt_ = (u32)(((kh_ * WP + kw_) << 9) + ((kc2_ & 7) << 6));       \
    _Pragma("unroll")                                                         \
    for (int g = 0; g < 4; ++g)                                               \
      gload16(xs + boffs[g] + bt_, &lB[((C) << 14) + ldst[g]]);               \
  } while (0)

#define STAGE_A(KC, C) do {                                                   \
    const u32 at_ = (u32)((KC) << 6);                                         \
    _Pragma("unroll")                                                         \
    for (int g = 0; g < 4; ++g)                                               \
      gload16(wb + aoffs[g] + at_, &lA[((C) << 14) + ldst[g]]);               \
  } while (0)

#define READ_A(PA, MH) do {                                                   \
    _Pragma("unroll")                                                         \
    for (int mq = 0; mq < 4; ++mq) {                                          \
      a0[mq][0] = *(const short8*)((PA) + (MH) * 4096 + mq * 1024 + sA0);     \
      a0[mq][1] = *(const short8*)((PA) + (MH) * 4096 + mq * 1024 + sA1);     \
    }                                                                         \
  } while (0)

#define READ_B(PB, NH, BV) do {                                               \
    _Pragma("unroll")                                                         \
    for (int nq = 0; nq < 2; ++nq) {                                          \
      BV[nq][0] = *(const short8*)((PB) + (NH) * 2048 + nq * 1024 + sA0);     \
      BV[nq][1] = *(const short8*)((PB) + (NH) * 2048 + nq * 1024 + sA1);     \
    }                                                                         \
  } while (0)

#define MFMA_Q(MH, NH, BV) do {                                               \
    _Pragma("unroll")                                                         \
    for (int kk = 0; kk < 2; ++kk)                                            \
      _Pragma("unroll")                                                       \
      for (int nq = 0; nq < 2; ++nq)                                          \
        _Pragma("unroll")                                                     \
        for (int mq = 0; mq < 4; ++mq)                                        \
          acc[(MH)*4+mq][(NH)*2+nq] = __builtin_amdgcn_mfma_f32_16x16x32_bf16(\
              a0[mq][kk], BV[nq][kk], acc[(MH)*4+mq][(NH)*2+nq], 0, 0, 0);    \
  } while (0)

#define BODY(T, DOSTAGE, WMODE) do {                                          \
    const int c_ = (T) & 1;                                                   \
    const u16* pA = lA + (c_ << 14) + aRead;                                  \
    const u16* pB = lB + (c_ << 14) + bRead;                                  \
    /* S1: read A-half0 + both B-halves, then 32 MFMA */                      \
    READ_A(pA, 0);                                                            \
    READ_B(pB, 0, b0);                                                        \
    READ_B(pB, 1, b1);                                                        \
    __builtin_amdgcn_s_barrier();                                             \
    __builtin_amdgcn_s_setprio(1);                                            \
    MFMA_Q(0, 0, b0); MFMA_Q(0, 1, b1);                                       \
    __builtin_amdgcn_s_setprio(0);                                            \
    __builtin_amdgcn_s_barrier();                                             \
    /* S2: stage B(t+2) (all lB reads done) + read A-half1, then 16 MFMA */   \
    __builtin_amdgcn_sched_barrier(0);                                        \
    if (DOSTAGE) STAGE_B((T) + 2, c_);                                        \
    READ_A(pA, 1);                                                            \
    __builtin_amdgcn_s_barrier();                                             \
    __builtin_amdgcn_s_setprio(1); MFMA_Q(1, 1, b1); __builtin_amdgcn_s_setprio(0); \
    __builtin_amdgcn_s_barrier();                                             \
    /* S3: stage A(t+2) (all lA reads done), interleaved with last 16 MFMA */ \
    __builtin_amdgcn_sched_barrier(0);                                        \
    if (DOSTAGE) STAGE_A((T) + 2, c_);                                        \
    __builtin_amdgcn_s_setprio(1); MFMA_Q(1, 0, b0); __builtin_amdgcn_s_setprio(0); \
    if (WMODE == 1)      asm volatile("s_waitcnt vmcnt(8)" ::: "memory");     \
    else if (WMODE == 2) asm volatile("s_waitcnt vmcnt(0)" ::: "memory");     \
    if (WMODE != 0) __builtin_amdgcn_s_barrier();                             \
  } while (0)

  // prologue: stage tiles 0 and 1, wait for tile 0 (8 newer stay in flight)
  STAGE_B(0, 0); STAGE_A(0, 0);
  STAGE_B(1, 1); STAGE_A(1, 1);
  asm volatile("s_waitcnt vmcnt(8)" ::: "memory");
  __builtin_amdgcn_sched_barrier(0);
  __builtin_amdgcn_s_barrier();

  for (int t = 0; t < 70; ++t) BODY(t, 1, 1);
  BODY(70, 0, 2);
  BODY(71, 0, 0);

#undef STAGE_B
#undef STAGE_A
#undef READ_A
#undef READ_B
#undef MFMA_Q
#undef BODY

  // epilogue: out = acc * d[b,o] + bias[o]; C/D: col=lane&15, row=(lane>>4)*4+r
  #pragma unroll
  for (int m = 0; m < 8; ++m) {
    #pragma unroll
    for (int r = 0; r < 4; ++r) {
      const int o = ob + (wr << 7) + (m << 4) + (k8 << 2) + r;
      const float dm = dmod[b * CO + o];
      const float bs = bias[o];
      float* po = out + (((size_t)(b * CO + o)) << 12) + p0 + (wc << 6);
      #pragma unroll
      for (int n = 0; n < 4; ++n)
        po[(n << 4) + col] = acc[m][n][r] * dm + bs;
    }
  }
}

extern "C" void kernel_launch(void* const* d_in, const int* in_sizes, int n_in,
                              void* d_out, int out_size, void* d_ws, size_t ws_size,
                              hipStream_t stream) {
  const float* x    = (const float*)d_in[0];
  const float* y    = (const float*)d_in[1];
  const float* aw   = (const float*)d_in[2];
  const float* ab   = (const float*)d_in[3];
  const float* wt   = (const float*)d_in[4];
  const float* bias = (const float*)d_in[5];
  float* out = (float*)d_out;

  char* ws = (char*)d_ws;
  const size_t XS_BYTES = (size_t)NB * HP * WP * CI * 2;     // 35,684,352
  const size_t WB_BYTES = (size_t)CO * 9 * CI * 2;           //  4,718,592
  const size_t WS_BYTES = (size_t)CO * CI * 4;               //  1,048,576
  u16* xsb    = (u16*)ws;
  u16* wbuf   = (u16*)(ws + XS_BYTES);
  float* wsum = (float*)(ws + XS_BYTES + WB_BYTES);
  float* sbuf = (float*)(ws + XS_BYTES + WB_BYTES + WS_BYTES);
  float* dbuf = sbuf + NB * CI;

  k_style<<<dim3(1024), dim3(256), 0, stream>>>(y, aw, ab, sbuf);
  k_wprep<<<dim3(1024), dim3(256), 0, stream>>>(wt, wsum, wbuf);
  k_demod<<<dim3(1024), dim3(256), 0, stream>>>(wsum, sbuf, dbuf);
  k_xform<<<dim3(4096), dim3(256), 0, stream>>>(x, sbuf, xsb);
  k_conv <<<dim3(256), dim3(512), 0, stream>>>(xsb, wbuf, dbuf, bias, out);
}

// Round 7
// 157.404 us; speedup vs baseline: 1.1648x; 1.0403x over previous
//
#include <hip/hip_runtime.h>

typedef __attribute__((ext_vector_type(8))) short short8;
typedef __attribute__((ext_vector_type(4))) float floatx4;
typedef unsigned short u16;
typedef unsigned int u32;

#define NB 8
#define CI 512
#define CO 512
#define HH 64
#define WW 64
#define HP 66
#define WP 66
#define BK 64

__device__ __forceinline__ u16 f2bf(float f) {
  u32 u = __builtin_bit_cast(u32, f);
  u += 0x7fffu + ((u >> 16) & 1u);
  return (u16)(u >> 16);
}

__device__ __forceinline__ void gload16(const void* g, void* l) {
  __builtin_amdgcn_global_load_lds(
      (const __attribute__((address_space(1))) unsigned int*)g,
      (__attribute__((address_space(3))) unsigned int*)l, 16, 0, 0);
}

// s[b,i] = coef * dot(y[b,:], affine_w[i,:]) + affine_b[i] + 1
__global__ __launch_bounds__(256) void k_style(
    const float* __restrict__ y, const float* __restrict__ aw,
    const float* __restrict__ ab, float* __restrict__ s)
{
  const int wid = blockIdx.x * 4 + (threadIdx.x >> 6);
  const int lane = threadIdx.x & 63;
  const int b = wid >> 9, i = wid & 511;
  float sum = 0.f;
  #pragma unroll
  for (int j = 0; j < 8; ++j) {
    const int k = lane + (j << 6);
    sum += y[b * CI + k] * aw[i * CI + k];
  }
  #pragma unroll
  for (int off = 32; off; off >>= 1) sum += __shfl_xor(sum, off);
  if (lane == 0) s[wid] = sum * 0.044194173824159216f + ab[i] + 1.0f;
}

// fused: wsum[o,i] = sum_t weight[o,i,t]^2 ; wb[(o*9+t)*512+i] = bf16(weight[o,i,t])
__global__ __launch_bounds__(256) void k_wprep(
    const float* __restrict__ wt, float* __restrict__ wsum, u16* __restrict__ wbv)
{
  const int idx = blockIdx.x * 256 + threadIdx.x;   // o*512+i
  const int i = idx & 511;
  const int o = idx >> 9;
  const float* p = wt + (size_t)idx * 9;
  float v[9];
  float sum = 0.f;
  #pragma unroll
  for (int t = 0; t < 9; ++t) { v[t] = p[t]; sum += v[t] * v[t]; }
  wsum[idx] = sum;
  #pragma unroll
  for (int t = 0; t < 9; ++t) wbv[(((o * 9 + t) << 9) | i)] = f2bf(v[t]);
}

// d[b,o] = rsqrt(sum_i wsum[o,i]*s[b,i]^2 + 1e-4)
__global__ __launch_bounds__(256) void k_demod(
    const float* __restrict__ wsum, const float* __restrict__ s,
    float* __restrict__ d)
{
  const int wid = blockIdx.x * 4 + (threadIdx.x >> 6);
  const int lane = threadIdx.x & 63;
  const int b = wid >> 9, o = wid & 511;
  float sum = 0.f;
  #pragma unroll
  for (int j = 0; j < 8; ++j) {
    const int i = lane + (j << 6);
    const float sv = s[b * CI + i];
    sum += wsum[o * CI + i] * sv * sv;
  }
  #pragma unroll
  for (int off = 32; off; off >>= 1) sum += __shfl_xor(sum, off);
  if (lane == 0) d[wid] = rsqrtf(sum + 1e-4f);
}

// xs[b, h+1, w+1, i] (NHWC, 66x66 padded, bf16) = x[b,i,h,w] * s[b,i]
// also zeroes its own slice of the halo border.
__global__ __launch_bounds__(256) void k_xform(
    const float* __restrict__ x, const float* __restrict__ s,
    u16* __restrict__ xs)
{
  __shared__ __align__(16) u16 lds[64 * 72];
  const int blk = blockIdx.x;          // ((b*64+h)*8 + ic)
  const int ic = blk & 7;
  const int h = (blk >> 3) & 63;
  const int b = blk >> 9;
  const int i0 = ic << 6;
  const int t = threadIdx.x;
  const int w = t & 63;
  const int i4 = t >> 6;
  #pragma unroll
  for (int p = 0; p < 16; ++p) {
    const int ii = i4 + (p << 2);
    const float xv = x[((size_t)(b * CI + i0 + ii) * HH + h) * WW + w];
    const float sv = s[b * CI + i0 + ii];
    lds[w * 72 + ii] = f2bf(xv * sv);
  }
  const uint4 z4 = {0u, 0u, 0u, 0u};
  if (t < 16) {
    const int wside = (t < 8) ? 0 : 65;
    const int q = t & 7;
    *(uint4*)&xs[((size_t)(b * HP + h + 1) * WP + wside) * CI + i0 + (q << 3)] = z4;
  }
  if (h == 0) {
    for (int idx = t; idx < 2 * 66 * 8; idx += 256) {
      const int row = (idx < 528) ? 0 : 65;
      const int rem = (idx < 528) ? idx : idx - 528;
      const int wz = rem >> 3;
      const int q = rem & 7;
      *(uint4*)&xs[((size_t)(b * HP + row) * WP + wz) * CI + i0 + (q << 3)] = z4;
    }
  }
  __syncthreads();
  const int w2 = t >> 2;
  const int q = t & 3;
  const uint4* src = (const uint4*)&lds[w2 * 72 + (q << 4)];
  const uint4 v0 = src[0];
  const uint4 v1 = src[1];
  u16* dst = xs + ((size_t)(b * HP + h + 1) * WP + (w2 + 1)) * CI + i0 + (q << 4);
  *(uint4*)dst = v0;
  *((uint4*)dst + 1) = v1;
}

// ---------------------------------------------------------------------------
// implicit-GEMM conv, m201-style 8-phase schedule, MFMA 16x16x32 bf16.
// BM=256 (O), BN=256 (pixels), BK=64, K = 9 taps x 512 = 72 tiles.
// One iter = 2 K-tiles (bufs 0,1 fixed), 8 phases; each phase:
//   {ds_reads for this C-quadrant | 1 half-tile stage (2 gload16)}
//   barrier; setprio(1); 16 MFMA; setprio(0); [vmcnt(4) at ph4/ph8]; barrier
// Staging order (each lands >=1 barrier after last read of its region):
//   ph1,2: A(T+1)->buf1   ph3,4: B(T+2)->buf0
//   ph5,6: A(T+2)->buf0   ph7,8: B(T+3)->buf1
// vmcnt(4): the 4 newest loads (current phase pair) are the only ones
// allowed outstanding -> tile about to be read has fully landed.
// ---------------------------------------------------------------------------
__global__ __launch_bounds__(512, 2) void k_conv(
    const u16* __restrict__ xs, const u16* __restrict__ wb,
    const float* __restrict__ dmod, const float* __restrict__ bias,
    float* __restrict__ out)
{
  __shared__ __align__(16) u16 lA[2 * 16384];
  __shared__ __align__(16) u16 lB[2 * 16384];

  const int blk = blockIdx.x;
  const int nt = blk & 15;
  const int mt = (blk >> 4) & 1;
  const int b  = blk >> 5;
  const int ob = mt << 8;
  const int p0 = nt << 8;

  const int tid = threadIdx.x;
  const int wid = tid >> 6;
  const int lane = tid & 63;
  const int col = lane & 15;
  const int k8  = lane >> 4;
  const int wr  = wid >> 2;          // wave M index (0..1)
  const int wc  = wid & 3;           // wave N index (0..3)

  // staging lane geometry: each gload16 stages 8 rows x 8 slots (1 KB).
  // source column pre-swizzled: lane l fetches slot (l&7)^(l>>3) of its row.
  const int lr = lane >> 3;
  const int ls = lane & 7;
  const int swz = ls ^ lr;

  // half-tile staging: half h (128 rows), sub g (2 gloads); idx = h*2+g.
  // rowIdx = h*128 + wid*16 + g*8 + lr  (8 waves x 16 rows = 128)
  u32 aoff[4], boff[4], ldst[4];
  #pragma unroll
  for (int h2 = 0; h2 < 4; ++h2) {
    const int rowBase = ((h2 >> 1) << 7) + (wid << 4) + ((h2 & 1) << 3);
    const int rowIdx = rowBase + lr;
    aoff[h2] = (u32)((ob + rowIdx) * 4608 + (swz << 3));
    const int p = p0 + rowIdx;
    boff[h2] = (u32)(((b * HP + (p >> 6)) * WP + (p & 63)) * 512 + (swz << 3));
    ldst[h2] = (u32)(rowBase << 6);
  }

  // ds_read swizzled slot offsets: slot (kk*4+k8) ^ (row&7), row&7 == col&7
  const u32 sA0 = (u32)(((0 + k8) ^ (col & 7)) << 3);
  const u32 sA1 = (u32)(((4 + k8) ^ (col & 7)) << 3);
  const u32 aRead = (u32)((((wr << 7) + col) << 6));
  const u32 bRead = (u32)((((wc << 6) + col) << 6));

  floatx4 acc[8][4];
  #pragma unroll
  for (int m = 0; m < 8; ++m)
    #pragma unroll
    for (int n = 0; n < 4; ++n)
      acc[m][n] = (floatx4){0.f, 0.f, 0.f, 0.f};

  short8 a0[4][2], b0[2][2], b1[2][2];

#define SA(TILE, H, BUF) do {                                                 \
    const u32 at_ = (u32)((TILE) << 6);                                       \
    gload16(wb + aoff[(H)*2+0] + at_, &lA[((BUF) << 14) + ldst[(H)*2+0]]);    \
    gload16(wb + aoff[(H)*2+1] + at_, &lA[((BUF) << 14) + ldst[(H)*2+1]]);    \
  } while (0)

#define SB(TILE, H, BUF) do {                                                 \
    const int t_ = (TILE);                                                    \
    const int tap_ = t_ >> 3;                                                 \
    const int kh_ = tap_ / 3;                                                 \
    const int kw_ = tap_ - kh_ * 3;                                           \
    const u32 bt_ = (u32)(((kh_ * WP + kw_) << 9) + ((t_ & 7) << 6));         \
    gload16(xs + boff[(H)*2+0] + bt_, &lB[((BUF) << 14) + ldst[(H)*2+0]]);    \
    gload16(xs + boff[(H)*2+1] + bt_, &lB[((BUF) << 14) + ldst[(H)*2+1]]);    \
  } while (0)

#define READ_A(PA, MH) do {                                                   \
    _Pragma("unroll")                                                         \
    for (int mq = 0; mq < 4; ++mq) {                                          \
      a0[mq][0] = *(const short8*)((PA) + (MH) * 4096 + mq * 1024 + sA0);     \
      a0[mq][1] = *(const short8*)((PA) + (MH) * 4096 + mq * 1024 + sA1);     \
    }                                                                         \
  } while (0)

#define READ_B(PB, NH, BV) do {                                               \
    _Pragma("unroll")                                                         \
    for (int nq = 0; nq < 2; ++nq) {                                          \
      BV[nq][0] = *(const short8*)((PB) + (NH) * 2048 + nq * 1024 + sA0);     \
      BV[nq][1] = *(const short8*)((PB) + (NH) * 2048 + nq * 1024 + sA1);     \
    }                                                                         \
  } while (0)

#define MFMA_Q(MH, NH, BV) do {                                               \
    _Pragma("unroll")                                                         \
    for (int kk = 0; kk < 2; ++kk)                                            \
      _Pragma("unroll")                                                       \
      for (int nq = 0; nq < 2; ++nq)                                          \
        _Pragma("unroll")                                                     \
        for (int mq = 0; mq < 4; ++mq)                                        \
          acc[(MH)*4+mq][(NH)*2+nq] = __builtin_amdgcn_mfma_f32_16x16x32_bf16(\
              a0[mq][kk], BV[nq][kk], acc[(MH)*4+mq][(NH)*2+nq], 0, 0, 0);    \
  } while (0)

#define SBAR __builtin_amdgcn_s_barrier()
#define SCH0 __builtin_amdgcn_sched_barrier(0)
#define PRI1 __builtin_amdgcn_s_setprio(1)
#define PRI0 __builtin_amdgcn_s_setprio(0)

#define BODY8(T0, FULL) do {                                                  \
    const u16* pA0 = lA + aRead;                                              \
    const u16* pB0 = lB + bRead;                                              \
    const u16* pA1 = lA + 16384 + aRead;                                      \
    const u16* pB1 = lB + 16384 + bRead;                                      \
    /* ph1: quad(0,0) of tile T0 (buf0) */                                    \
    READ_A(pA0, 0); READ_B(pB0, 0, b0);                                       \
    SCH0; SA((T0) + 1, 0, 1);                                                 \
    SBAR; PRI1; MFMA_Q(0, 0, b0); PRI0; SBAR;                                 \
    /* ph2: quad(0,1) */                                                      \
    READ_B(pB0, 1, b1);                                                       \
    SCH0; SA((T0) + 1, 1, 1);                                                 \
    SBAR; PRI1; MFMA_Q(0, 1, b1); PRI0; SBAR;                                 \
    /* ph3: quad(1,1) — B(buf0) fully read after ph2 */                       \
    READ_A(pA0, 1);                                                           \
    SCH0; if (FULL) SB((T0) + 2, 0, 0);                                       \
    SBAR; PRI1; MFMA_Q(1, 1, b1); PRI0; SBAR;                                 \
    /* ph4: quad(1,0) — vmcnt: tile T0+1 fully landed */                      \
    SCH0; if (FULL) SB((T0) + 2, 1, 0);                                       \
    SBAR; PRI1; MFMA_Q(1, 0, b0); PRI0;                                       \
    if (FULL) asm volatile("s_waitcnt vmcnt(4)" ::: "memory");                \
    else      asm volatile("s_waitcnt vmcnt(0)" ::: "memory");                \
    SBAR;                                                                     \
    /* ph5: quad(0,0) of tile T0+1 (buf1) — A(buf0) fully read after ph3 */   \
    READ_A(pA1, 0); READ_B(pB1, 0, b0);                                       \
    SCH0; if (FULL) SA((T0) + 2, 0, 0);                                       \
    SBAR; PRI1; MFMA_Q(0, 0, b0); PRI0; SBAR;                                 \
    /* ph6: quad(0,1) */                                                      \
    READ_B(pB1, 1, b1);                                                       \
    SCH0; if (FULL) SA((T0) + 2, 1, 0);                                       \
    SBAR; PRI1; MFMA_Q(0, 1, b1); PRI0; SBAR;                                 \
    /* ph7: quad(1,1) — B(buf1) fully read after ph6 */                       \
    READ_A(pA1, 1);                                                           \
    SCH0; if (FULL) SB((T0) + 3, 0, 1);                                       \
    SBAR; PRI1; MFMA_Q(1, 1, b1); PRI0; SBAR;                                 \
    /* ph8: quad(1,0) — vmcnt: tile T0+2 fully landed */                      \
    SCH0; if (FULL) SB((T0) + 3, 1, 1);                                       \
    SBAR; PRI1; MFMA_Q(1, 0, b0); PRI0;                                       \
    if (FULL) asm volatile("s_waitcnt vmcnt(4)" ::: "memory");                \
    SBAR;                                                                     \
  } while (0)

  // prologue: tile0 full + tile1-B; vmcnt(4) leaves tile1-B in flight.
  SB(0, 0, 0); SB(0, 1, 0); SA(0, 0, 0); SA(0, 1, 0);
  SB(1, 0, 1); SB(1, 1, 1);
  asm volatile("s_waitcnt vmcnt(4)" ::: "memory");
  SCH0;
  SBAR;

  for (int j = 0; j < 35; ++j) BODY8(j * 2, 1);
  BODY8(70, 0);

#undef SA
#undef SB
#undef READ_A
#undef READ_B
#undef MFMA_Q
#undef BODY8
#undef SBAR
#undef SCH0
#undef PRI1
#undef PRI0

  // epilogue: out = acc * d[b,o] + bias[o]; C/D: col=lane&15, row=(lane>>4)*4+r
  #pragma unroll
  for (int m = 0; m < 8; ++m) {
    #pragma unroll
    for (int r = 0; r < 4; ++r) {
      const int o = ob + (wr << 7) + (m << 4) + (k8 << 2) + r;
      const float dm = dmod[b * CO + o];
      const float bs = bias[o];
      float* po = out + (((size_t)(b * CO + o)) << 12) + p0 + (wc << 6);
      #pragma unroll
      for (int n = 0; n < 4; ++n)
        po[(n << 4) + col] = acc[m][n][r] * dm + bs;
    }
  }
}

extern "C" void kernel_launch(void* const* d_in, const int* in_sizes, int n_in,
                              void* d_out, int out_size, void* d_ws, size_t ws_size,
                              hipStream_t stream) {
  const float* x    = (const float*)d_in[0];
  const float* y    = (const float*)d_in[1];
  const float* aw   = (const float*)d_in[2];
  const float* ab   = (const float*)d_in[3];
  const float* wt   = (const float*)d_in[4];
  const float* bias = (const float*)d_in[5];
  float* out = (float*)d_out;

  char* ws = (char*)d_ws;
  const size_t XS_BYTES = (size_t)NB * HP * WP * CI * 2;     // 35,684,352
  const size_t WB_BYTES = (size_t)CO * 9 * CI * 2;           //  4,718,592
  const size_t WS_BYTES = (size_t)CO * CI * 4;               //  1,048,576
  u16* xsb    = (u16*)ws;
  u16* wbuf   = (u16*)(ws + XS_BYTES);
  float* wsum = (float*)(ws + XS_BYTES + WB_BYTES);
  float* sbuf = (float*)(ws + XS_BYTES + WB_BYTES + WS_BYTES);
  float* dbuf = sbuf + NB * CI;

  k_style<<<dim3(1024), dim3(256), 0, stream>>>(y, aw, ab, sbuf);
  k_wprep<<<dim3(1024), dim3(256), 0, stream>>>(wt, wsum, wbuf);
  k_demod<<<dim3(1024), dim3(256), 0, stream>>>(wsum, sbuf, dbuf);
  k_xform<<<dim3(4096), dim3(256), 0, stream>>>(x, sbuf, xsb);
  k_conv <<<dim3(256), dim3(512), 0, stream>>>(xsb, wbuf, dbuf, bias, out);
}